// Round 1
// baseline (621.186 us; speedup 1.0000x reference)
//
#include <hip/hip_runtime.h>
#include <hip/hip_bf16.h>

// THLSTM cell fused kernel, MI355X (gfx950).
// Strategy: convert weights to bf16 once per launch into d_ws (concat per gate,
// [Hout,K] row-major), then one fused kernel: LDS-staged [h|x|s] A-tile (bf16),
// 16x16x32 bf16 MFMA GEMMs, incremental elementwise combine in registers.

constexpr int Btot = 65536;
constexpr int H    = 256;
constexpr int I    = 128;
constexpr int K1   = 384;   // [h|x]
constexpr int K2   = 640;   // [h|x|s]
constexpr int BT   = 64;    // batch rows per WG
constexpr int NTHR = 512;   // 8 waves
constexpr int LSTR = 648;   // LDS row stride (bf16 elems), 640 + 8 pad

typedef __bf16 bf16x8 __attribute__((ext_vector_type(8)));
typedef float  f32x4  __attribute__((ext_vector_type(4)));

__device__ __forceinline__ unsigned short f2bf(float f) {
    unsigned u = __builtin_bit_cast(unsigned, f);
    u += 0x7fffu + ((u >> 16) & 1u);   // round-to-nearest-even
    return (unsigned short)(u >> 16);
}
__device__ __forceinline__ float bf2f(unsigned short s) {
    return __builtin_bit_cast(float, ((unsigned)s) << 16);
}
__device__ __forceinline__ float sigm(float x) {
    return __builtin_amdgcn_rcpf(1.0f + exp2f(-1.4426950408889634f * x));
}
__device__ __forceinline__ float tanh_f(float x) {
    // tanh(x) = 1 - 2/(exp(2x)+1)
    return 1.0f - 2.0f * __builtin_amdgcn_rcpf(1.0f + exp2f(2.8853900817779268f * x));
}

// Build bf16 weight copies: w0 = [Wh0|Wx0] as [256][384]; wg = 5 x [256][640] = [Whg|Wxg|Ws(g-1)]
__global__ void convert_w(const float* __restrict__ Wh, const float* __restrict__ Wx,
                          const float* __restrict__ Ws, unsigned short* __restrict__ w0,
                          unsigned short* __restrict__ wgate) {
    const int t  = blockIdx.x * blockDim.x + threadIdx.x;
    const int N0 = H * K1;
    const int N1 = 5 * H * K2;
    if (t < N0) {
        const int o = t / K1, k = t % K1;
        const float v = (k < H) ? Wh[o * H + k] : Wx[o * I + (k - H)];
        w0[t] = f2bf(v);
    } else if (t < N0 + N1) {
        const int u  = t - N0;
        const int g1 = u / (H * K2);          // 0..4, gate = g1+1
        const int rem = u - g1 * (H * K2);
        const int o = rem / K2, k = rem % K2;
        const int g = g1 + 1;
        float v;
        if (k < H)        v = Wh[g * H * H + o * H + k];
        else if (k < K1)  v = Wx[g * H * I + o * I + (k - H)];
        else              v = Ws[g1 * H * H + o * H + (k - K1)];
        wgate[u] = f2bf(v);
    }
}

// One GEMM tile: acc[2][4] covers 32 rows x 64 cols per wave.
// A operand from LDS (rows = batch), B operand = weight rows [Hout][K] from global (L2).
__device__ __forceinline__ void gemm_k(const unsigned short A[BT][LSTR],
                                       const unsigned short* __restrict__ W,
                                       int Krun, int Wstride,
                                       int mb, int ob, int lr, int kg,
                                       f32x4 acc[2][4]) {
    for (int kt = 0; kt < Krun; kt += 32) {
        const int k0 = kt + kg;
        const bf16x8 a0 = *(const bf16x8*)&A[mb + lr][k0];
        const bf16x8 a1 = *(const bf16x8*)&A[mb + 16 + lr][k0];
        #pragma unroll
        for (int nt = 0; nt < 4; ++nt) {
            const bf16x8 bfr = *(const bf16x8*)&W[(size_t)(ob + nt * 16 + lr) * Wstride + k0];
            acc[0][nt] = __builtin_amdgcn_mfma_f32_16x16x32_bf16(a0, bfr, acc[0][nt], 0, 0, 0);
            acc[1][nt] = __builtin_amdgcn_mfma_f32_16x16x32_bf16(a1, bfr, acc[1][nt], 0, 0, 0);
        }
    }
}

__global__ __launch_bounds__(NTHR) void thlstm_fused(
        const float* __restrict__ x_t, const float* __restrict__ delta_t,
        const float* __restrict__ h_prev, const float* __restrict__ c_prev,
        const float* __restrict__ Wst, const float* __restrict__ bias,
        const unsigned short* __restrict__ w0, const unsigned short* __restrict__ wgate,
        float* __restrict__ out) {
    __shared__ __align__(16) unsigned short A[BT][LSTR];  // [h(256)|x(128)|s(256)] bf16, padded
    __shared__ float dlt[BT];
    const int tid = threadIdx.x;
    const int b0  = blockIdx.x * BT;

    // Stage h (64x256) and x (64x128) as bf16 into LDS.
    for (int i = tid; i < BT * (H / 4); i += NTHR) {
        const int row = i >> 6, c4 = i & 63;
        const float4 v = *(const float4*)&h_prev[(size_t)(b0 + row) * H + c4 * 4];
        ushort4 s; s.x = f2bf(v.x); s.y = f2bf(v.y); s.z = f2bf(v.z); s.w = f2bf(v.w);
        *(ushort4*)&A[row][c4 * 4] = s;
    }
    for (int i = tid; i < BT * (I / 4); i += NTHR) {
        const int row = i >> 5, c4 = i & 31;
        const float4 v = *(const float4*)&x_t[(size_t)(b0 + row) * I + c4 * 4];
        ushort4 s; s.x = f2bf(v.x); s.y = f2bf(v.y); s.z = f2bf(v.z); s.w = f2bf(v.w);
        *(ushort4*)&A[row][H + c4 * 4] = s;
    }
    if (tid < BT) dlt[tid] = delta_t[b0 + tid];
    __syncthreads();

    const int lane = tid & 63;
    const int wv   = tid >> 6;        // 0..7
    const int mb   = (wv >> 2) * 32;  // wave row base: 0 or 32
    const int ob   = (wv & 3) * 64;   // wave col base: 0,64,128,192
    const int lr   = lane & 15;       // row/col-in-tile
    const int kg   = (lane >> 4) * 8; // K-offset per lane group
    const int dm   = (lane >> 4) * 4; // D-row base per lane group

    const f32x4 vzero = {0.f, 0.f, 0.f, 0.f};

    // ---- gate s: K=384 over [h|x] ----
    f32x4 acc[2][4];
    #pragma unroll
    for (int mt = 0; mt < 2; ++mt)
        #pragma unroll
        for (int nt = 0; nt < 4; ++nt) acc[mt][nt] = vzero;
    gemm_k(A, w0, K1, K1, mb, ob, lr, kg, acc);
    #pragma unroll
    for (int mt = 0; mt < 2; ++mt)
        #pragma unroll
        for (int nt = 0; nt < 4; ++nt)
            #pragma unroll
            for (int r = 0; r < 4; ++r) {
                const int m = mb + mt * 16 + dm + r;
                const int o = ob + nt * 16 + lr;
                const float pre = acc[mt][nt][r] + dlt[m] * Wst[o] + bias[o];
                A[m][K1 + o] = f2bf(tanh_f(pre));  // s_t into LDS A-tile k in [384,640)
            }
    __syncthreads();

    // ---- gates f,i,T,u,o: K=640 over [h|x|s], incremental combine ----
    float cacc[2][4][4];
    float iv[2][4][4];
    #pragma unroll
    for (int g = 1; g <= 5; ++g) {
        f32x4 acc2[2][4];
        #pragma unroll
        for (int mt = 0; mt < 2; ++mt)
            #pragma unroll
            for (int nt = 0; nt < 4; ++nt) acc2[mt][nt] = vzero;
        gemm_k(A, wgate + (size_t)(g - 1) * H * K2, K2, K2, mb, ob, lr, kg, acc2);
        #pragma unroll
        for (int mt = 0; mt < 2; ++mt)
            #pragma unroll
            for (int nt = 0; nt < 4; ++nt)
                #pragma unroll
                for (int r = 0; r < 4; ++r) {
                    const int m = mb + mt * 16 + dm + r;
                    const int o = ob + nt * 16 + lr;
                    const float pre = acc2[mt][nt][r] + bias[g * H + o];
                    if (g == 1) {          // f: c = f * c_prev
                        cacc[mt][nt][r] = sigm(pre) * c_prev[(size_t)(b0 + m) * H + o];
                    } else if (g == 2) {   // i
                        iv[mt][nt][r] = sigm(pre);
                    } else if (g == 3) {   // T: c += T * s_t
                        cacc[mt][nt][r] += sigm(pre) * bf2f(A[m][K1 + o]);
                    } else if (g == 4) {   // u: c += i * tanh(u)
                        cacc[mt][nt][r] += iv[mt][nt][r] * tanh_f(pre);
                    } else {               // o: outputs
                        const float c = cacc[mt][nt][r];
                        out[(size_t)(b0 + m) * H + o] = sigm(pre) * tanh_f(c);
                        out[(size_t)Btot * H + (size_t)(b0 + m) * H + o] = c;
                    }
                }
    }
}

extern "C" void kernel_launch(void* const* d_in, const int* in_sizes, int n_in,
                              void* d_out, int out_size, void* d_ws, size_t ws_size,
                              hipStream_t stream) {
    (void)in_sizes; (void)n_in; (void)out_size; (void)ws_size;
    const float* x_t    = (const float*)d_in[0];
    const float* delta  = (const float*)d_in[1];
    const float* h_prev = (const float*)d_in[2];
    const float* c_prev = (const float*)d_in[3];
    const float* Wh     = (const float*)d_in[4];
    const float* Wx     = (const float*)d_in[5];
    const float* Ws     = (const float*)d_in[6];
    const float* Wst    = (const float*)d_in[7];
    const float* bias   = (const float*)d_in[8];
    float* out = (float*)d_out;

    unsigned short* w0 = (unsigned short*)d_ws;              // 256*384 bf16
    unsigned short* wg = w0 + H * K1;                        // 5*256*640 bf16

    const int total = H * K1 + 5 * H * K2;                   // 917504
    convert_w<<<(total + 255) / 256, 256, 0, stream>>>(Wh, Wx, Ws, w0, wg);
    thlstm_fused<<<Btot / BT, NTHR, 0, stream>>>(x_t, delta, h_prev, c_prev,
                                                 Wst, bias, w0, wg, out);
}

// Round 2
// 604.569 us; speedup vs baseline: 1.0275x; 1.0275x over previous
//
#include <hip/hip_runtime.h>
#include <hip/hip_bf16.h>

// THLSTM cell fused, MI355X gfx950 — round 2.
// 32x32x16 bf16 MFMA, XOR-swizzled 80KB LDS A-tile [64 rows][640 K], 8 waves
// with distinct 32-col output slices, full-line 128B stores, unrolled K loops.

constexpr int Btot = 65536;
constexpr int H    = 256;
constexpr int I    = 128;
constexpr int K1   = 384;   // [h|x]
constexpr int K2   = 640;   // [h|x|s]
constexpr int BT   = 64;    // batch rows per WG
constexpr int NTHR = 512;   // 8 waves

typedef __bf16 bf16x8  __attribute__((ext_vector_type(8)));
typedef float  f32x16  __attribute__((ext_vector_type(16)));
typedef unsigned short ushort8 __attribute__((ext_vector_type(8)));

__device__ __forceinline__ unsigned short f2bf(float f) {
    unsigned u = __builtin_bit_cast(unsigned, f);
    u += 0x7fffu + ((u >> 16) & 1u);   // RNE
    return (unsigned short)(u >> 16);
}
__device__ __forceinline__ float bf2f(unsigned short s) {
    return __builtin_bit_cast(float, ((unsigned)s) << 16);
}
__device__ __forceinline__ float sigm(float x) {
    return __builtin_amdgcn_rcpf(1.0f + exp2f(-1.4426950408889634f * x));
}
__device__ __forceinline__ float tanh_f(float x) {
    return 1.0f - 2.0f * __builtin_amdgcn_rcpf(1.0f + exp2f(2.8853900817779268f * x));
}

// bf16 weight copies: w0 = [Wh0|Wx0] as [256][384]; wg = 5 x [256][640] = [Whg|Wxg|Ws(g-1)]
__global__ void convert_w(const float* __restrict__ Wh, const float* __restrict__ Wx,
                          const float* __restrict__ Ws, unsigned short* __restrict__ w0,
                          unsigned short* __restrict__ wgate) {
    const int t  = blockIdx.x * blockDim.x + threadIdx.x;
    const int N0 = H * K1;
    const int N1 = 5 * H * K2;
    if (t < N0) {
        const int o = t / K1, k = t % K1;
        const float v = (k < H) ? Wh[o * H + k] : Wx[o * I + (k - H)];
        w0[t] = f2bf(v);
    } else if (t < N0 + N1) {
        const int u   = t - N0;
        const int g1  = u / (H * K2);
        const int rem = u - g1 * (H * K2);
        const int o = rem / K2, k = rem % K2;
        const int g = g1 + 1;
        float v;
        if (k < H)        v = Wh[g * H * H + o * H + k];
        else if (k < K1)  v = Wx[g * H * I + o * I + (k - H)];
        else              v = Ws[g1 * H * H + o * H + (k - K1)];
        wgate[u] = f2bf(v);
    }
}

// swizzled LDS byte offset for A-tile: row in [0,64), kb = byte offset in row [0,1280)
__device__ __forceinline__ int swz(int row, int kb) {
    return row * 1280 + (kb ^ ((row & 7) << 4));
}

__global__ __launch_bounds__(NTHR, 4) void thlstm_fused(
        const float* __restrict__ x_t, const float* __restrict__ delta_t,
        const float* __restrict__ h_prev, const float* __restrict__ c_prev,
        const float* __restrict__ Wst, const float* __restrict__ bias,
        const unsigned short* __restrict__ w0, const unsigned short* __restrict__ wgate,
        float* __restrict__ out) {
    __shared__ __align__(16) unsigned char Abuf[BT * 1280];   // 80 KB exactly
    const int tid = threadIdx.x;
    const int b0  = blockIdx.x * BT;

    // ---- stage h|x as bf16 into swizzled LDS (16B chunks) ----
    #pragma unroll
    for (int it = 0; it < (BT * 48) / NTHR; ++it) {
        const int c   = it * NTHR + tid;
        const int row = c / 48, seg = c % 48;
        const float* src = (seg < 32)
            ? (h_prev + (size_t)(b0 + row) * H + seg * 8)
            : (x_t    + (size_t)(b0 + row) * I + (seg - 32) * 8);
        const float4 v0 = ((const float4*)src)[0];
        const float4 v1 = ((const float4*)src)[1];
        ushort8 p;
        p[0] = f2bf(v0.x); p[1] = f2bf(v0.y); p[2] = f2bf(v0.z); p[3] = f2bf(v0.w);
        p[4] = f2bf(v1.x); p[5] = f2bf(v1.y); p[6] = f2bf(v1.z); p[7] = f2bf(v1.w);
        *(ushort8*)&Abuf[swz(row, seg * 16)] = p;
    }
    __syncthreads();

    const int lane = tid & 63;
    const int wv   = tid >> 6;           // 0..7
    const int ob   = wv * 32;            // distinct 32-col slice per wave
    const int lrow = lane & 31;
    const int kgrp = (lane >> 5) * 8;    // K sub-offset per half-wave
    const int ocol = ob + lrow;
    const int rbase = 4 * (lane >> 5);   // C/D row contribution from lane

    // ---- gate s: K=384 ----
    f32x16 acc0, acc1;
    #pragma unroll
    for (int r = 0; r < 16; ++r) { acc0[r] = 0.f; acc1[r] = 0.f; }
    #pragma unroll 8
    for (int kt = 0; kt < K1; kt += 16) {
        const int kb = (kt + kgrp) * 2;
        const bf16x8 a0 = *(const bf16x8*)&Abuf[swz(lrow,      kb)];
        const bf16x8 a1 = *(const bf16x8*)&Abuf[swz(32 + lrow, kb)];
        const bf16x8 b  = *(const bf16x8*)&w0[ocol * K1 + kt + kgrp];
        acc0 = __builtin_amdgcn_mfma_f32_32x32x16_bf16(a0, b, acc0, 0, 0, 0);
        acc1 = __builtin_amdgcn_mfma_f32_32x32x16_bf16(a1, b, acc1, 0, 0, 0);
    }
    {
        const float wst = Wst[ocol];
        const float bs  = bias[ocol];
        #pragma unroll
        for (int t = 0; t < 2; ++t)
            #pragma unroll
            for (int r = 0; r < 16; ++r) {
                const int m = t * 32 + (r & 3) + 8 * (r >> 2) + rbase;
                const float pre = (t ? acc1[r] : acc0[r]) + delta_t[b0 + m] * wst + bs;
                *(unsigned short*)&Abuf[swz(m, 768 + ocol * 2)] = f2bf(tanh_f(pre));
            }
    }
    __syncthreads();

    // ---- gates f,T,i,u,o (wgate order f,i,T,u,o -> process 0,2,1,3,4) ----
    float cacc[2][16];
    float iv[2][16];
    constexpr int gseq[5] = {0, 2, 1, 3, 4};
    #pragma unroll
    for (int j = 0; j < 5; ++j) {
        const int g = gseq[j];
        const unsigned short* __restrict__ W = wgate + (size_t)g * H * K2;
        f32x16 ac0, ac1;
        #pragma unroll
        for (int r = 0; r < 16; ++r) { ac0[r] = 0.f; ac1[r] = 0.f; }
        #pragma unroll 10
        for (int kt = 0; kt < K2; kt += 16) {
            const int kb = (kt + kgrp) * 2;
            const bf16x8 a0 = *(const bf16x8*)&Abuf[swz(lrow,      kb)];
            const bf16x8 a1 = *(const bf16x8*)&Abuf[swz(32 + lrow, kb)];
            const bf16x8 b  = *(const bf16x8*)&W[ocol * K2 + kt + kgrp];
            ac0 = __builtin_amdgcn_mfma_f32_32x32x16_bf16(a0, b, ac0, 0, 0, 0);
            ac1 = __builtin_amdgcn_mfma_f32_32x32x16_bf16(a1, b, ac1, 0, 0, 0);
        }
        const float bg = bias[(g + 1) * H + ocol];
        #pragma unroll
        for (int t = 0; t < 2; ++t)
            #pragma unroll
            for (int r = 0; r < 16; ++r) {
                const int m = t * 32 + (r & 3) + 8 * (r >> 2) + rbase;
                const float pre = (t ? ac1[r] : ac0[r]) + bg;
                const size_t idx = (size_t)(b0 + m) * H + ocol;
                if (g == 0) {                 // f: c = f * c_prev
                    cacc[t][r] = sigm(pre) * c_prev[idx];
                } else if (g == 2) {          // T: c += T * s (s from LDS)
                    const float sv = bf2f(*(const unsigned short*)&Abuf[swz(m, 768 + ocol * 2)]);
                    cacc[t][r] += sigm(pre) * sv;
                } else if (g == 1) {          // i
                    iv[t][r] = sigm(pre);
                } else if (g == 3) {          // u: c += i * tanh(u)
                    cacc[t][r] += iv[t][r] * tanh_f(pre);
                } else {                      // o: outputs
                    const float c = cacc[t][r];
                    out[idx] = sigm(pre) * tanh_f(c);
                    out[(size_t)Btot * H + idx] = c;
                }
            }
    }
}

extern "C" void kernel_launch(void* const* d_in, const int* in_sizes, int n_in,
                              void* d_out, int out_size, void* d_ws, size_t ws_size,
                              hipStream_t stream) {
    (void)in_sizes; (void)n_in; (void)out_size; (void)ws_size;
    const float* x_t    = (const float*)d_in[0];
    const float* delta  = (const float*)d_in[1];
    const float* h_prev = (const float*)d_in[2];
    const float* c_prev = (const float*)d_in[3];
    const float* Wh     = (const float*)d_in[4];
    const float* Wx     = (const float*)d_in[5];
    const float* Ws     = (const float*)d_in[6];
    const float* Wst    = (const float*)d_in[7];
    const float* bias   = (const float*)d_in[8];
    float* out = (float*)d_out;

    unsigned short* w0 = (unsigned short*)d_ws;   // 256*384 bf16
    unsigned short* wg = w0 + H * K1;             // 5*256*640 bf16

    const int total = H * K1 + 5 * H * K2;        // 917504
    convert_w<<<(total + 255) / 256, 256, 0, stream>>>(Wh, Wx, Ws, w0, wg);
    thlstm_fused<<<Btot / BT, NTHR, 0, stream>>>(x_t, delta, h_prev, c_prev,
                                                 Wst, bias, w0, wg, out);
}

// Round 3
// 344.819 us; speedup vs baseline: 1.8015x; 1.7533x over previous
//
#include <hip/hip_runtime.h>
#include <hip/hip_bf16.h>

// THLSTM cell fused, MI355X gfx950 — round 3.
// Fragment-order LDS A-tile (lane-linear ds_read_b128, conflict-free),
// [k8][col][8] coalesced bf16 weights, 32x32x16 MFMA, rotating prefetch,
// no spills (launch_bounds(512,2)), gate order f,T,i,u,o with packed i_t.

constexpr int Btot = 65536;
constexpr int H    = 256;
constexpr int I    = 128;
constexpr int K1   = 384;   // [h|x]
constexpr int K2   = 640;   // [h|x|s]
constexpr int BT   = 64;    // batch rows per WG
constexpr int NTHR = 512;   // 8 waves
constexpr int REG1 = 40960; // LDS region stride (bytes): 32 rows x 80 k8 x 16B

typedef __bf16 bf16x8  __attribute__((ext_vector_type(8)));
typedef float  f32x16  __attribute__((ext_vector_type(16)));
typedef unsigned short ushort8 __attribute__((ext_vector_type(8)));

__device__ __forceinline__ unsigned short f2bf(float f) {
    unsigned u = __builtin_bit_cast(unsigned, f);
    u += 0x7fffu + ((u >> 16) & 1u);   // RNE
    return (unsigned short)(u >> 16);
}
__device__ __forceinline__ float bf2f(unsigned short s) {
    return __builtin_bit_cast(float, ((unsigned)s) << 16);
}
__device__ __forceinline__ float sigm(float x) {
    return __builtin_amdgcn_rcpf(1.0f + exp2f(-1.4426950408889634f * x));
}
__device__ __forceinline__ float tanh_f(float x) {
    return 1.0f - 2.0f * __builtin_amdgcn_rcpf(1.0f + exp2f(2.8853900817779268f * x));
}

// Weights to bf16, layout [k8][col][8]: elem (col, k=k8*8+e) at (k8*256+col)*8+e.
// w0: 48 k8 (K=384), per gate wg: 80 k8 (K=640), 5 gates (f,i,T,u,o).
__global__ void convert_w(const float* __restrict__ Wh, const float* __restrict__ Wx,
                          const float* __restrict__ Ws, unsigned short* __restrict__ w0,
                          unsigned short* __restrict__ wg) {
    const int t  = blockIdx.x * blockDim.x + threadIdx.x;
    const int N0 = 48 * 2048;        // 98304
    const int N1 = 5 * 80 * 2048;    // 819200
    if (t < N0) {
        const int k8 = t >> 11, rem = t & 2047;
        const int col = rem >> 3, e = rem & 7;
        const int k = k8 * 8 + e;
        const float v = (k < H) ? Wh[col * H + k] : Wx[col * I + (k - H)];
        w0[t] = f2bf(v);
    } else if (t < N0 + N1) {
        const int u   = t - N0;
        const int g1  = u / 163840;
        const int rem = u - g1 * 163840;
        const int k8  = rem >> 11;
        const int r2  = rem & 2047;
        const int col = r2 >> 3, e = r2 & 7;
        const int k   = k8 * 8 + e;
        const int g   = g1 + 1;
        float v;
        if (k < H)        v = Wh[g * H * H + col * H + k];
        else if (k < K1)  v = Wx[g * H * I + col * I + (k - H)];
        else              v = Ws[g1 * H * H + col * H + (k - K1)];
        wg[u] = f2bf(v);
    }
}

// K-loop with rotating 1-ahead prefetch. a-reads lane-linear: base + i*1024 + lane*16.
template<int NIT>
__device__ __forceinline__ void gemm_pipe(const unsigned char* Ab, int abase,
        const unsigned short* __restrict__ Wp, f32x16& acc0, f32x16& acc1) {
    bf16x8 a0c = *(const bf16x8*)(Ab + abase);
    bf16x8 a1c = *(const bf16x8*)(Ab + REG1 + abase);
    bf16x8 bc  = *(const bf16x8*)(Wp);
    #pragma unroll 4
    for (int i = 0; i < NIT - 1; ++i) {
        const bf16x8 a0n = *(const bf16x8*)(Ab + abase + (i + 1) * 1024);
        const bf16x8 a1n = *(const bf16x8*)(Ab + REG1 + abase + (i + 1) * 1024);
        const bf16x8 bn  = *(const bf16x8*)(Wp + (i + 1) * 4096);
        acc0 = __builtin_amdgcn_mfma_f32_32x32x16_bf16(a0c, bc, acc0, 0, 0, 0);
        acc1 = __builtin_amdgcn_mfma_f32_32x32x16_bf16(a1c, bc, acc1, 0, 0, 0);
        a0c = a0n; a1c = a1n; bc = bn;
    }
    acc0 = __builtin_amdgcn_mfma_f32_32x32x16_bf16(a0c, bc, acc0, 0, 0, 0);
    acc1 = __builtin_amdgcn_mfma_f32_32x32x16_bf16(a1c, bc, acc1, 0, 0, 0);
}

__global__ __launch_bounds__(NTHR, 2) void thlstm_fused(
        const float* __restrict__ x_t, const float* __restrict__ delta_t,
        const float* __restrict__ h_prev, const float* __restrict__ c_prev,
        const float* __restrict__ Wst, const float* __restrict__ bias,
        const unsigned short* __restrict__ w0, const unsigned short* __restrict__ wg,
        float* __restrict__ out) {
    __shared__ __align__(16) unsigned char Abuf[BT * 1280];   // 80 KB
    const int tid = threadIdx.x;
    const int b0  = blockIdx.x * BT;

    // ---- stage h|x as bf16, fragment order: chunk(region,row32,k8) at reg*REG1+(k8*32+row32)*16
    #pragma unroll
    for (int it = 0; it < 6; ++it) {
        const int c   = it * NTHR + tid;
        const int k8  = c >> 6, row = c & 63;
        const float* src = (k8 < 32) ? (h_prev + (size_t)(b0 + row) * H + k8 * 8)
                                     : (x_t    + (size_t)(b0 + row) * I + (k8 - 32) * 8);
        const float4 v0 = ((const float4*)src)[0];
        const float4 v1 = ((const float4*)src)[1];
        ushort8 p;
        p[0] = f2bf(v0.x); p[1] = f2bf(v0.y); p[2] = f2bf(v0.z); p[3] = f2bf(v0.w);
        p[4] = f2bf(v1.x); p[5] = f2bf(v1.y); p[6] = f2bf(v1.z); p[7] = f2bf(v1.w);
        *(ushort8*)(Abuf + (row >> 5) * REG1 + (k8 * 32 + (row & 31)) * 16) = p;
    }
    __syncthreads();

    const int lane  = tid & 63;
    const int wv    = tid >> 6;
    const int half  = lane >> 5;
    const int l31   = lane & 31;
    const int ocol  = wv * 32 + l31;
    const int rbase = 4 * half;
    const int abase = lane * 16;
    const int wlo   = half * 2048 + ocol * 8;
    const int sbase = (48 + (ocol >> 3)) * 512 + (ocol & 7) * 2;  // s slot within region

    // ---- gate s: K=384 ----
    {
        f32x16 acc0, acc1;
        #pragma unroll
        for (int r = 0; r < 16; ++r) { acc0[r] = 0.f; acc1[r] = 0.f; }
        gemm_pipe<24>(Abuf, abase, w0 + wlo, acc0, acc1);
        const float wst = Wst[ocol];
        const float bs  = bias[ocol];
        #pragma unroll
        for (int t = 0; t < 2; ++t)
            #pragma unroll
            for (int r = 0; r < 16; ++r) {
                const int mrow = (r & 3) + 8 * (r >> 2) + rbase;
                const float av = t ? acc1[r] : acc0[r];
                const float pre = av + delta_t[b0 + t * 32 + mrow] * wst + bs;
                *(unsigned short*)(Abuf + t * REG1 + sbase + mrow * 16) = f2bf(tanh_f(pre));
            }
    }
    __syncthreads();

    float    cacc[2][16];
    unsigned ipk[2][8];

    // ---- gate f (wg 0, bias 1): c = f * c_prev ----
    {
        f32x16 ac0, ac1;
        #pragma unroll
        for (int r = 0; r < 16; ++r) { ac0[r] = 0.f; ac1[r] = 0.f; }
        gemm_pipe<40>(Abuf, abase, wg + 0 * 163840 + wlo, ac0, ac1);
        const float bg = bias[1 * H + ocol];
        #pragma unroll
        for (int t = 0; t < 2; ++t)
            #pragma unroll
            for (int r = 0; r < 16; ++r) {
                const int mrow = (r & 3) + 8 * (r >> 2) + rbase;
                const size_t idx = (size_t)(b0 + t * 32 + mrow) * H + ocol;
                const float pre = (t ? ac1[r] : ac0[r]) + bg;
                cacc[t][r] = sigm(pre) * c_prev[idx];
            }
    }
    // ---- gate T (wg 2, bias 3): c += T * s (s from LDS) ----
    {
        f32x16 ac0, ac1;
        #pragma unroll
        for (int r = 0; r < 16; ++r) { ac0[r] = 0.f; ac1[r] = 0.f; }
        gemm_pipe<40>(Abuf, abase, wg + 2 * 163840 + wlo, ac0, ac1);
        const float bg = bias[3 * H + ocol];
        #pragma unroll
        for (int t = 0; t < 2; ++t)
            #pragma unroll
            for (int r = 0; r < 16; ++r) {
                const int mrow = (r & 3) + 8 * (r >> 2) + rbase;
                const float sv = bf2f(*(const unsigned short*)(Abuf + t * REG1 + sbase + mrow * 16));
                const float pre = (t ? ac1[r] : ac0[r]) + bg;
                cacc[t][r] += sigm(pre) * sv;
            }
    }
    // ---- gate i (wg 1, bias 2): keep packed ----
    {
        f32x16 ac0, ac1;
        #pragma unroll
        for (int r = 0; r < 16; ++r) { ac0[r] = 0.f; ac1[r] = 0.f; }
        gemm_pipe<40>(Abuf, abase, wg + 1 * 163840 + wlo, ac0, ac1);
        const float bg = bias[2 * H + ocol];
        #pragma unroll
        for (int t = 0; t < 2; ++t) {
            float tmpf = 0.f;
            #pragma unroll
            for (int r = 0; r < 16; ++r) {
                const float pre = (t ? ac1[r] : ac0[r]) + bg;
                const float sg = sigm(pre);
                if ((r & 1) == 0) tmpf = sg;
                else ipk[t][r >> 1] = (unsigned)f2bf(tmpf) | ((unsigned)f2bf(sg) << 16);
            }
        }
    }
    // ---- gate u (wg 3, bias 4): c += i * tanh(u) ----
    {
        f32x16 ac0, ac1;
        #pragma unroll
        for (int r = 0; r < 16; ++r) { ac0[r] = 0.f; ac1[r] = 0.f; }
        gemm_pipe<40>(Abuf, abase, wg + 3 * 163840 + wlo, ac0, ac1);
        const float bg = bias[4 * H + ocol];
        #pragma unroll
        for (int t = 0; t < 2; ++t)
            #pragma unroll
            for (int r = 0; r < 16; ++r) {
                const float pre = (t ? ac1[r] : ac0[r]) + bg;
                const float iv = bf2f((unsigned short)((ipk[t][r >> 1] >> ((r & 1) * 16)) & 0xffffu));
                cacc[t][r] += iv * tanh_f(pre);
            }
    }
    // ---- gate o (wg 4, bias 5): outputs ----
    {
        f32x16 ac0, ac1;
        #pragma unroll
        for (int r = 0; r < 16; ++r) { ac0[r] = 0.f; ac1[r] = 0.f; }
        gemm_pipe<40>(Abuf, abase, wg + 4 * 163840 + wlo, ac0, ac1);
        const float bg = bias[5 * H + ocol];
        #pragma unroll
        for (int t = 0; t < 2; ++t)
            #pragma unroll
            for (int r = 0; r < 16; ++r) {
                const int mrow = (r & 3) + 8 * (r >> 2) + rbase;
                const size_t idx = (size_t)(b0 + t * 32 + mrow) * H + ocol;
                const float pre = (t ? ac1[r] : ac0[r]) + bg;
                const float c = cacc[t][r];
                out[idx] = sigm(pre) * tanh_f(c);
                out[(size_t)Btot * H + idx] = c;
            }
    }
}

extern "C" void kernel_launch(void* const* d_in, const int* in_sizes, int n_in,
                              void* d_out, int out_size, void* d_ws, size_t ws_size,
                              hipStream_t stream) {
    (void)in_sizes; (void)n_in; (void)out_size; (void)ws_size;
    const float* x_t    = (const float*)d_in[0];
    const float* delta  = (const float*)d_in[1];
    const float* h_prev = (const float*)d_in[2];
    const float* c_prev = (const float*)d_in[3];
    const float* Wh     = (const float*)d_in[4];
    const float* Wx     = (const float*)d_in[5];
    const float* Ws     = (const float*)d_in[6];
    const float* Wst    = (const float*)d_in[7];
    const float* bias   = (const float*)d_in[8];
    float* out = (float*)d_out;

    unsigned short* w0 = (unsigned short*)d_ws;   // 48*2048 bf16
    unsigned short* wg = w0 + 48 * 2048;          // 5*80*2048 bf16

    const int total = 48 * 2048 + 5 * 80 * 2048;  // 917504
    convert_w<<<(total + 255) / 256, 256, 0, stream>>>(Wh, Wx, Ws, w0, wg);
    thlstm_fused<<<Btot / BT, NTHR, 0, stream>>>(x_t, delta, h_prev, c_prev,
                                                 Wst, bias, w0, wg, out);
}